// Round 1
// baseline (1591.233 us; speedup 1.0000x reference)
//
#include <hip/hip_runtime.h>
#include <hip/hip_bf16.h>
#include <stdint.h>

#define NTOK 4096
#define DM   1024
#define HD   4096
#define NE   8
#define NS   8192      // NTOK * top_k
#define TEMP 1.5f
#define LNEPS 1e-5f
#define BM 128
#define BN 128

typedef __attribute__((ext_vector_type(8))) short bf16x8;
typedef __attribute__((ext_vector_type(4))) float f32x4;
typedef unsigned short u16;

__device__ inline void glds16(const void* g, void* l) {
  __builtin_amdgcn_global_load_lds((const __attribute__((address_space(1))) unsigned int*)g,
                                   (__attribute__((address_space(3))) unsigned int*)l, 16, 0, 0);
}
__device__ inline u16 f2b(float f) {
  __hip_bfloat16 h = __float2bfloat16(f);
  return *reinterpret_cast<u16*>(&h);
}
__device__ inline float b2f(u16 u) { return __uint_as_float(((unsigned int)u) << 16); }

// ---------------- LayerNorm + router + top2 ----------------
__global__ __launch_bounds__(256) void k_ln_router(
    const float* __restrict__ x, const float* __restrict__ gamma, const float* __restrict__ beta,
    const float* __restrict__ rw, u16* __restrict__ xnb,
    int* __restrict__ e01, float* __restrict__ w01, int* __restrict__ counts) {
  int t = blockIdx.x;
  int tid = threadIdx.x, lane = tid & 63, wv = tid >> 6;
  float4 v = ((const float4*)(x + (size_t)t * DM))[tid];
  float s  = v.x + v.y + v.z + v.w;
  float s2 = v.x*v.x + v.y*v.y + v.z*v.z + v.w*v.w;
  for (int o = 32; o > 0; o >>= 1) { s += __shfl_down(s, o); s2 += __shfl_down(s2, o); }
  __shared__ float rs_[4], rs2_[4];
  if (lane == 0) { rs_[wv] = s; rs2_[wv] = s2; }
  __syncthreads();
  float sum  = rs_[0] + rs_[1] + rs_[2] + rs_[3];
  float sum2 = rs2_[0] + rs2_[1] + rs2_[2] + rs2_[3];
  float mu = sum * (1.f / DM);
  float var = sum2 * (1.f / DM) - mu * mu;
  float rstd = rsqrtf(var + LNEPS);
  float4 g4 = ((const float4*)gamma)[tid];
  float4 b4 = ((const float4*)beta)[tid];
  float n0 = (v.x - mu) * rstd * g4.x + b4.x;
  float n1 = (v.y - mu) * rstd * g4.y + b4.y;
  float n2 = (v.z - mu) * rstd * g4.z + b4.z;
  float n3 = (v.w - mu) * rstd * g4.w + b4.w;
  ushort4 pk; pk.x = f2b(n0); pk.y = f2b(n1); pk.z = f2b(n2); pk.w = f2b(n3);
  *(ushort4*)(xnb + (size_t)t * DM + tid * 4) = pk;
  // router logits in fp32 from exact xn
  float p[NE];
#pragma unroll
  for (int e = 0; e < NE; e++) {
    float4 r = ((const float4*)(rw + (size_t)e * DM))[tid];
    p[e] = n0 * r.x + n1 * r.y + n2 * r.z + n3 * r.w;
  }
#pragma unroll
  for (int e = 0; e < NE; e++)
    for (int o = 32; o > 0; o >>= 1) p[e] += __shfl_down(p[e], o);
  __shared__ float plds[4][NE];
  if (lane == 0) {
#pragma unroll
    for (int e = 0; e < NE; e++) plds[wv][e] = p[e];
  }
  __syncthreads();
  if (tid == 0) {
    float lg[NE], mx = -1e30f;
#pragma unroll
    for (int e = 0; e < NE; e++) {
      lg[e] = plds[0][e] + plds[1][e] + plds[2][e] + plds[3][e];
      mx = fmaxf(mx, lg[e]);
    }
    float ex[NE], ssum = 0.f;
#pragma unroll
    for (int e = 0; e < NE; e++) { ex[e] = __expf((lg[e] - mx) * (1.f / TEMP)); ssum += ex[e]; }
    float inv = 1.f / ssum;
    float p0 = -1e30f, p1 = -1e30f; int i0 = 0, i1 = 1;
#pragma unroll
    for (int e = 0; e < NE; e++) {
      float pe = ex[e] * inv;
      if (pe > p0) { p1 = p0; i1 = i0; p0 = pe; i0 = e; }
      else if (pe > p1) { p1 = pe; i1 = e; }
    }
    e01[2*t] = i0; e01[2*t+1] = i1; w01[2*t] = p0; w01[2*t+1] = p1;
    atomicAdd(&counts[i0], 1); atomicAdd(&counts[i1], 1);
  }
}

// ---------------- tiny exclusive scan over 8 counts ----------------
__global__ void k_scan(const int* __restrict__ counts, int* __restrict__ off) {
  if (threadIdx.x == 0) {
    int a = 0;
    for (int e = 0; e < NE; e++) { off[e] = a; a += counts[e]; }
    off[NE] = a;
  }
}

// ---------------- bucket tokens into compact expert lists ----------------
__global__ void k_bucket(const int* __restrict__ e01, const float* __restrict__ w01,
                         const int* __restrict__ off, int* fill, int* __restrict__ list,
                         float* __restrict__ wlist, int* __restrict__ slots) {
  int t = blockIdx.x * blockDim.x + threadIdx.x;
  if (t >= NTOK) return;
  for (int j = 0; j < 2; j++) {
    int e = e01[2*t+j];
    int pos = atomicAdd(&fill[e], 1);
    int s = off[e] + pos;
    list[s] = t; wlist[s] = w01[2*t+j]; slots[2*t+j] = s;
  }
}

// ---------------- transpose + fp32->bf16 (per expert slice) ----------------
__global__ __launch_bounds__(256) void k_transpose(const float* __restrict__ in,
                                                   u16* __restrict__ out, int R, int C) {
  __shared__ float tile[32][33];
  size_t base = (size_t)blockIdx.z * R * C;
  int r0 = blockIdx.x << 5, c0 = blockIdx.y << 5;
  int tx = threadIdx.x, ty = threadIdx.y;
#pragma unroll
  for (int k = 0; k < 4; k++)
    tile[ty + 8*k][tx] = in[base + (size_t)(r0 + ty + 8*k) * C + (c0 + tx)];
  __syncthreads();
#pragma unroll
  for (int k = 0; k < 4; k++)
    out[base + (size_t)(c0 + ty + 8*k) * R + (r0 + tx)] = f2b(tile[tx][ty + 8*k]);
}

// ---------------- GEMM1: h = silu(xn @ W1[e]), gathered rows ----------------
__global__ __launch_bounds__(256) void k_gemm1(
    const u16* __restrict__ xnb, const u16* __restrict__ W1t,
    const int* __restrict__ list, const int* __restrict__ off, const int* __restrict__ counts,
    u16* __restrict__ hbuf) {
  int e = blockIdx.x >> 5, tm = blockIdx.x & 31;
  int cnt = counts[e];
  if (tm * BM >= cnt) return;
  int seg = off[e];
  int tn = blockIdx.y;
  __shared__ __attribute__((aligned(16))) u16 sA[4*128*8];
  __shared__ __attribute__((aligned(16))) u16 sB[4*128*8];
  int tid = threadIdx.x, lane = tid & 63, wv = tid >> 6;
  int wm = (wv >> 1) << 6, wn = (wv & 1) << 6;
  int r0 = tm*BM + lane, r1 = r0 + 64;
  int tok0 = list[seg + min(r0, cnt - 1)];
  int tok1 = list[seg + min(r1, cnt - 1)];
  const u16* a0 = xnb + (size_t)tok0 * DM;
  const u16* a1 = xnb + (size_t)tok1 * DM;
  const u16* b0 = W1t + ((size_t)e*HD + (size_t)tn*BN + lane) * DM;
  const u16* b1 = b0 + (size_t)64 * DM;
  u16* dA0 = sA + (wv*128 +  0)*8;
  u16* dA1 = sA + (wv*128 + 64)*8;
  u16* dB0 = sB + (wv*128 +  0)*8;
  u16* dB1 = sB + (wv*128 + 64)*8;
  f32x4 acc[4][4];
#pragma unroll
  for (int i = 0; i < 4; i++)
#pragma unroll
    for (int j = 0; j < 4; j++) acc[i][j] = (f32x4){0.f, 0.f, 0.f, 0.f};
  for (int k0 = 0; k0 < DM; k0 += 32) {
    int ks = k0 + wv*8;
    glds16(a0 + ks, dA0);
    glds16(a1 + ks, dA1);
    glds16(b0 + ks, dB0);
    glds16(b1 + ks, dB1);
    __syncthreads();
    int g = lane >> 4, mr = lane & 15;
    bf16x8 af[4], bfr[4];
#pragma unroll
    for (int i = 0; i < 4; i++) af[i]  = *(const bf16x8*)(sA + ((g*128) + wm + i*16 + mr)*8);
#pragma unroll
    for (int i = 0; i < 4; i++) bfr[i] = *(const bf16x8*)(sB + ((g*128) + wn + i*16 + mr)*8);
#pragma unroll
    for (int i = 0; i < 4; i++)
#pragma unroll
      for (int j = 0; j < 4; j++)
        acc[i][j] = __builtin_amdgcn_mfma_f32_16x16x32_bf16(af[i], bfr[j], acc[i][j], 0, 0, 0);
    __syncthreads();
  }
  int g = lane >> 4, c = lane & 15;
#pragma unroll
  for (int i = 0; i < 4; i++) {
#pragma unroll
    for (int rr = 0; rr < 4; rr++) {
      int row = wm + i*16 + g*4 + rr;
      if (tm*BM + row < cnt) {
        size_t rbase = (size_t)(seg + tm*BM + row) * HD + (size_t)tn*BN + wn + c;
#pragma unroll
        for (int j = 0; j < 4; j++) {
          float vv = acc[i][j][rr];
          float sv = vv / (1.f + __expf(-vv));   // silu
          hbuf[rbase + j*16] = f2b(sv);
        }
      }
    }
  }
}

// ---------------- GEMM2: y = (h @ W2[e]) * w_row ----------------
__global__ __launch_bounds__(256) void k_gemm2(
    const u16* __restrict__ hbuf, const u16* __restrict__ W2t,
    const float* __restrict__ wlist, const int* __restrict__ off, const int* __restrict__ counts,
    u16* __restrict__ ybuf) {
  int e = blockIdx.x >> 5, tm = blockIdx.x & 31;
  int cnt = counts[e];
  if (tm * BM >= cnt) return;
  int seg = off[e];
  int tn = blockIdx.y;   // 0..7
  __shared__ __attribute__((aligned(16))) u16 sA[4*128*8];
  __shared__ __attribute__((aligned(16))) u16 sB[4*128*8];
  int tid = threadIdx.x, lane = tid & 63, wv = tid >> 6;
  int wm = (wv >> 1) << 6, wn = (wv & 1) << 6;
  int r0 = seg + tm*BM + lane;      if (r0 > NS-1) r0 = NS-1;
  int r1 = seg + tm*BM + 64 + lane; if (r1 > NS-1) r1 = NS-1;
  const u16* a0 = hbuf + (size_t)r0 * HD;
  const u16* a1 = hbuf + (size_t)r1 * HD;
  const u16* b0 = W2t + ((size_t)e*DM + (size_t)tn*BN + lane) * HD;
  const u16* b1 = b0 + (size_t)64 * HD;
  u16* dA0 = sA + (wv*128 +  0)*8;
  u16* dA1 = sA + (wv*128 + 64)*8;
  u16* dB0 = sB + (wv*128 +  0)*8;
  u16* dB1 = sB + (wv*128 + 64)*8;
  f32x4 acc[4][4];
#pragma unroll
  for (int i = 0; i < 4; i++)
#pragma unroll
    for (int j = 0; j < 4; j++) acc[i][j] = (f32x4){0.f, 0.f, 0.f, 0.f};
  for (int k0 = 0; k0 < HD; k0 += 32) {
    int ks = k0 + wv*8;
    glds16(a0 + ks, dA0);
    glds16(a1 + ks, dA1);
    glds16(b0 + ks, dB0);
    glds16(b1 + ks, dB1);
    __syncthreads();
    int g = lane >> 4, mr = lane & 15;
    bf16x8 af[4], bfr[4];
#pragma unroll
    for (int i = 0; i < 4; i++) af[i]  = *(const bf16x8*)(sA + ((g*128) + wm + i*16 + mr)*8);
#pragma unroll
    for (int i = 0; i < 4; i++) bfr[i] = *(const bf16x8*)(sB + ((g*128) + wn + i*16 + mr)*8);
#pragma unroll
    for (int i = 0; i < 4; i++)
#pragma unroll
      for (int j = 0; j < 4; j++)
        acc[i][j] = __builtin_amdgcn_mfma_f32_16x16x32_bf16(af[i], bfr[j], acc[i][j], 0, 0, 0);
    __syncthreads();
  }
  int g = lane >> 4, c = lane & 15;
#pragma unroll
  for (int i = 0; i < 4; i++) {
#pragma unroll
    for (int rr = 0; rr < 4; rr++) {
      int row = wm + i*16 + g*4 + rr;
      if (tm*BM + row < cnt) {
        int s = seg + tm*BM + row;
        float wgt = wlist[s];
        size_t rbase = (size_t)s * DM + (size_t)tn*BN + wn + c;
#pragma unroll
        for (int j = 0; j < 4; j++)
          ybuf[rbase + j*16] = f2b(acc[i][j][rr] * wgt);
      }
    }
  }
}

// ---------------- combine: out = x + y[slot0] + y[slot1] ----------------
__global__ __launch_bounds__(256) void k_combine(const float* __restrict__ x,
    const u16* __restrict__ ybuf, const int* __restrict__ slots, float* __restrict__ out) {
  int t = blockIdx.x, tid = threadIdx.x;
  int sA = slots[2*t], sB = slots[2*t+1];
  float4 xv = ((const float4*)(x + (size_t)t * DM))[tid];
  ushort4 ya = *(const ushort4*)(ybuf + (size_t)sA * DM + tid * 4);
  ushort4 yb = *(const ushort4*)(ybuf + (size_t)sB * DM + tid * 4);
  float4 o;
  o.x = xv.x + b2f(ya.x) + b2f(yb.x);
  o.y = xv.y + b2f(ya.y) + b2f(yb.y);
  o.z = xv.z + b2f(ya.z) + b2f(yb.z);
  o.w = xv.w + b2f(ya.w) + b2f(yb.w);
  ((float4*)(out + (size_t)t * DM))[tid] = o;
}

extern "C" void kernel_launch(void* const* d_in, const int* in_sizes, int n_in,
                              void* d_out, int out_size, void* d_ws, size_t ws_size,
                              hipStream_t stream) {
  const float* x     = (const float*)d_in[0];
  const float* gamma = (const float*)d_in[1];
  const float* beta  = (const float*)d_in[2];
  const float* rw    = (const float*)d_in[3];
  const float* W1    = (const float*)d_in[4];
  const float* W2    = (const float*)d_in[5];
  float* out = (float*)d_out;

  char* w = (char*)d_ws;
  size_t o = 0;
  auto alloc = [&](size_t bytes) -> void* {
    void* p = w + o; o = (o + bytes + 255) & ~(size_t)255; return p;
  };
  u16*   xnb   = (u16*)  alloc((size_t)NTOK * DM * 2);
  u16*   W1t   = (u16*)  alloc((size_t)NE * HD * DM * 2);
  u16*   W2t   = (u16*)  alloc((size_t)NE * DM * HD * 2);
  u16*   hbuf  = (u16*)  alloc((size_t)NS * HD * 2);
  u16*   ybuf  = (u16*)  alloc((size_t)NS * DM * 2);
  int*   e01   = (int*)  alloc((size_t)NTOK * 2 * 4);
  float* w01   = (float*)alloc((size_t)NTOK * 2 * 4);
  int*   slots = (int*)  alloc((size_t)NTOK * 2 * 4);
  int*   list  = (int*)  alloc((size_t)NS * 4);
  float* wlist = (float*)alloc((size_t)NS * 4);
  int*   meta  = (int*)  alloc(256);          // counts[8], fill[8], off[9]
  int* counts = meta;
  int* fill   = meta + 8;
  int* off    = meta + 16;

  hipMemsetAsync(meta, 0, 256, stream);
  k_ln_router<<<NTOK, 256, 0, stream>>>(x, gamma, beta, rw, xnb, e01, w01, counts);
  k_scan<<<1, 64, 0, stream>>>(counts, off);
  k_bucket<<<NTOK / 256, 256, 0, stream>>>(e01, w01, off, fill, list, wlist, slots);
  k_transpose<<<dim3(DM/32, HD/32, NE), dim3(32, 8), 0, stream>>>(W1, W1t, DM, HD);
  k_transpose<<<dim3(HD/32, DM/32, NE), dim3(32, 8), 0, stream>>>(W2, W2t, HD, DM);
  k_gemm1<<<dim3(NE * 32, HD / BN), 256, 0, stream>>>(xnb, W1t, list, off, counts, hbuf);
  k_gemm2<<<dim3(NE * 32, DM / BN), 256, 0, stream>>>(hbuf, W2t, wlist, off, counts, ybuf);
  k_combine<<<NTOK, 256, 0, stream>>>(x, ybuf, slots, out);
}

// Round 2
// 1226.077 us; speedup vs baseline: 1.2978x; 1.2978x over previous
//
#include <hip/hip_runtime.h>
#include <hip/hip_bf16.h>
#include <stdint.h>

#define NTOK 4096
#define DM   1024
#define HD   4096
#define NE   8
#define NS   8192      // NTOK * top_k
#define TEMP 1.5f
#define LNEPS 1e-5f
#define BM 128
#define BN 128
#define BK 64          // k-chunk per K-loop iteration (8 chunks of 8 bf16 = 16B each)

typedef __attribute__((ext_vector_type(8))) short bf16x8;
typedef __attribute__((ext_vector_type(4))) float f32x4;
typedef unsigned short u16;

__device__ inline void glds16(const void* g, void* l) {
  __builtin_amdgcn_global_load_lds((const __attribute__((address_space(1))) unsigned int*)g,
                                   (__attribute__((address_space(3))) unsigned int*)l, 16, 0, 0);
}
__device__ inline u16 f2b(float f) {
  __hip_bfloat16 h = __float2bfloat16(f);
  return *reinterpret_cast<u16*>(&h);
}
__device__ inline float b2f(u16 u) { return __uint_as_float(((unsigned int)u) << 16); }

// ---------------- LayerNorm + router + top2 ----------------
__global__ __launch_bounds__(256) void k_ln_router(
    const float* __restrict__ x, const float* __restrict__ gamma, const float* __restrict__ beta,
    const float* __restrict__ rw, u16* __restrict__ xnb,
    int* __restrict__ e01, float* __restrict__ w01, int* __restrict__ counts) {
  int t = blockIdx.x;
  int tid = threadIdx.x, lane = tid & 63, wv = tid >> 6;
  float4 v = ((const float4*)(x + (size_t)t * DM))[tid];
  float s  = v.x + v.y + v.z + v.w;
  float s2 = v.x*v.x + v.y*v.y + v.z*v.z + v.w*v.w;
  for (int o = 32; o > 0; o >>= 1) { s += __shfl_down(s, o); s2 += __shfl_down(s2, o); }
  __shared__ float rs_[4], rs2_[4];
  if (lane == 0) { rs_[wv] = s; rs2_[wv] = s2; }
  __syncthreads();
  float sum  = rs_[0] + rs_[1] + rs_[2] + rs_[3];
  float sum2 = rs2_[0] + rs2_[1] + rs2_[2] + rs2_[3];
  float mu = sum * (1.f / DM);
  float var = sum2 * (1.f / DM) - mu * mu;
  float rstd = rsqrtf(var + LNEPS);
  float4 g4 = ((const float4*)gamma)[tid];
  float4 b4 = ((const float4*)beta)[tid];
  float n0 = (v.x - mu) * rstd * g4.x + b4.x;
  float n1 = (v.y - mu) * rstd * g4.y + b4.y;
  float n2 = (v.z - mu) * rstd * g4.z + b4.z;
  float n3 = (v.w - mu) * rstd * g4.w + b4.w;
  ushort4 pk; pk.x = f2b(n0); pk.y = f2b(n1); pk.z = f2b(n2); pk.w = f2b(n3);
  *(ushort4*)(xnb + (size_t)t * DM + tid * 4) = pk;
  float p[NE];
#pragma unroll
  for (int e = 0; e < NE; e++) {
    float4 r = ((const float4*)(rw + (size_t)e * DM))[tid];
    p[e] = n0 * r.x + n1 * r.y + n2 * r.z + n3 * r.w;
  }
#pragma unroll
  for (int e = 0; e < NE; e++)
    for (int o = 32; o > 0; o >>= 1) p[e] += __shfl_down(p[e], o);
  __shared__ float plds[4][NE];
  if (lane == 0) {
#pragma unroll
    for (int e = 0; e < NE; e++) plds[wv][e] = p[e];
  }
  __syncthreads();
  if (tid == 0) {
    float lg[NE], mx = -1e30f;
#pragma unroll
    for (int e = 0; e < NE; e++) {
      lg[e] = plds[0][e] + plds[1][e] + plds[2][e] + plds[3][e];
      mx = fmaxf(mx, lg[e]);
    }
    float ex[NE], ssum = 0.f;
#pragma unroll
    for (int e = 0; e < NE; e++) { ex[e] = __expf((lg[e] - mx) * (1.f / TEMP)); ssum += ex[e]; }
    float inv = 1.f / ssum;
    float p0 = -1e30f, p1 = -1e30f; int i0 = 0, i1 = 1;
#pragma unroll
    for (int e = 0; e < NE; e++) {
      float pe = ex[e] * inv;
      if (pe > p0) { p1 = p0; i1 = i0; p0 = pe; i0 = e; }
      else if (pe > p1) { p1 = pe; i1 = e; }
    }
    e01[2*t] = i0; e01[2*t+1] = i1; w01[2*t] = p0; w01[2*t+1] = p1;
    atomicAdd(&counts[i0], 1); atomicAdd(&counts[i1], 1);
  }
}

// ---------------- tiny exclusive scan over 8 counts ----------------
__global__ void k_scan(const int* __restrict__ counts, int* __restrict__ off) {
  if (threadIdx.x == 0) {
    int a = 0;
    for (int e = 0; e < NE; e++) { off[e] = a; a += counts[e]; }
    off[NE] = a;
  }
}

// ---------------- bucket tokens into compact expert lists ----------------
__global__ void k_bucket(const int* __restrict__ e01, const float* __restrict__ w01,
                         const int* __restrict__ off, int* fill, int* __restrict__ list,
                         float* __restrict__ wlist, int* __restrict__ slots) {
  int t = blockIdx.x * blockDim.x + threadIdx.x;
  if (t >= NTOK) return;
  for (int j = 0; j < 2; j++) {
    int e = e01[2*t+j];
    int pos = atomicAdd(&fill[e], 1);
    int s = off[e] + pos;
    list[s] = t; wlist[s] = w01[2*t+j]; slots[2*t+j] = s;
  }
}

// ---------------- transpose + fp32->bf16, 64x64 tile, vectorized ----------------
__global__ __launch_bounds__(256) void k_transpose(const float* __restrict__ in,
                                                   u16* __restrict__ out, int R, int C) {
  __shared__ u16 t[64][68];
  size_t base = (size_t)blockIdx.z * (size_t)R * C;
  int r0 = blockIdx.x << 6, c0 = blockIdx.y << 6;
  int tid = threadIdx.x;
  int rr = tid >> 4, c4 = tid & 15;
#pragma unroll
  for (int p = 0; p < 4; p++) {
    int r = p * 16 + rr;
    float4 v = *(const float4*)(in + base + (size_t)(r0 + r) * C + c0 + c4 * 4);
    ushort4 pk; pk.x = f2b(v.x); pk.y = f2b(v.y); pk.z = f2b(v.z); pk.w = f2b(v.w);
    *(ushort4*)&t[r][c4 * 4] = pk;
  }
  __syncthreads();
#pragma unroll
  for (int p = 0; p < 4; p++) {
    int cc = p * 16 + rr;    // output row (= input column)
    ushort4 o;
    o.x = t[c4*4 + 0][cc]; o.y = t[c4*4 + 1][cc];
    o.z = t[c4*4 + 2][cc]; o.w = t[c4*4 + 3][cc];
    *(ushort4*)(out + base + (size_t)(c0 + cc) * R + r0 + c4 * 4) = o;
  }
}

// ---------------- GEMM1: h = silu(xn @ W1t^T), gathered rows ----------------
// Staging: each glds16 instruction covers 8 consecutive rows x 8 chunks (full 128B
// lines). LDS is row-major [row][BK] with chunk XOR-swizzle (chunk ^ row&7) to
// keep fragment ds_read_b128 conflict-free.
__global__ __launch_bounds__(256) void k_gemm1(
    const u16* __restrict__ xnb, const u16* __restrict__ W1t,
    const int* __restrict__ list, const int* __restrict__ off, const int* __restrict__ counts,
    u16* __restrict__ hbuf) {
  int e = blockIdx.x >> 5, tm = blockIdx.x & 31;
  int cnt = counts[e];
  if (tm * BM >= cnt) return;
  int seg = off[e];
  int tn = blockIdx.y;
  __shared__ __attribute__((aligned(16))) u16 sA[BM * BK];
  __shared__ __attribute__((aligned(16))) u16 sB[BN * BK];
  int tid = threadIdx.x, lane = tid & 63, wv = tid >> 6;
  int wm = (wv >> 1) << 6, wn = (wv & 1) << 6;
  int rsub = lane >> 3;          // 0..7 row within 8-row group
  int ch   = lane & 7;           // chunk slot in LDS
  int cs   = ch ^ rsub;          // swizzled global chunk to fetch
  const u16* aptr[4]; const u16* bptr[4];
  u16* dA[4]; u16* dB[4];
#pragma unroll
  for (int j = 0; j < 4; j++) {
    int r = wv * 32 + j * 8 + rsub;              // row within 128-tile
    int tok = list[seg + min(tm * BM + r, cnt - 1)];
    aptr[j] = xnb + (size_t)tok * DM + cs * 8;
    bptr[j] = W1t + ((size_t)e * HD + tn * BN + r) * DM + cs * 8;
    dA[j] = sA + (wv * 32 + j * 8) * BK;         // wave-uniform base
    dB[j] = sB + (wv * 32 + j * 8) * BK;
  }
  f32x4 acc[4][4];
#pragma unroll
  for (int i = 0; i < 4; i++)
#pragma unroll
    for (int j = 0; j < 4; j++) acc[i][j] = (f32x4){0.f, 0.f, 0.f, 0.f};
  int g = lane >> 4, mr = lane & 15;
#pragma unroll 1
  for (int k0 = 0; k0 < DM; k0 += BK) {
#pragma unroll
    for (int j = 0; j < 4; j++) { glds16(aptr[j] + k0, dA[j]); glds16(bptr[j] + k0, dB[j]); }
    __syncthreads();
    int oa[4], ob[4];
    bf16x8 af[4], bfr[4];
#pragma unroll
    for (int i = 0; i < 4; i++) {
      int ra = wm + i * 16 + mr;
      int rb = wn + i * 16 + mr;
      oa[i] = ra * BK + ((g ^ (ra & 7)) << 3);
      ob[i] = rb * BK + ((g ^ (rb & 7)) << 3);
      af[i]  = *(const bf16x8*)(sA + oa[i]);
      bfr[i] = *(const bf16x8*)(sB + ob[i]);
    }
#pragma unroll
    for (int i = 0; i < 4; i++)
#pragma unroll
      for (int j = 0; j < 4; j++)
        acc[i][j] = __builtin_amdgcn_mfma_f32_16x16x32_bf16(af[i], bfr[j], acc[i][j], 0, 0, 0);
#pragma unroll
    for (int i = 0; i < 4; i++) {
      af[i]  = *(const bf16x8*)(sA + (oa[i] ^ 32));   // chunks 4..7 (k 32..63)
      bfr[i] = *(const bf16x8*)(sB + (ob[i] ^ 32));
    }
#pragma unroll
    for (int i = 0; i < 4; i++)
#pragma unroll
      for (int j = 0; j < 4; j++)
        acc[i][j] = __builtin_amdgcn_mfma_f32_16x16x32_bf16(af[i], bfr[j], acc[i][j], 0, 0, 0);
    __syncthreads();
  }
  int c = lane & 15;
#pragma unroll
  for (int i = 0; i < 4; i++) {
#pragma unroll
    for (int rr2 = 0; rr2 < 4; rr2++) {
      int row = wm + i * 16 + g * 4 + rr2;
      if (tm * BM + row < cnt) {
        size_t rbase = (size_t)(seg + tm * BM + row) * HD + (size_t)tn * BN + wn + c;
#pragma unroll
        for (int j = 0; j < 4; j++) {
          float vv = acc[i][j][rr2];
          float sv = vv / (1.f + __expf(-vv));   // silu
          hbuf[rbase + j * 16] = f2b(sv);
        }
      }
    }
  }
}

// ---------------- GEMM2: y = (h @ W2t^T) * w_row ----------------
__global__ __launch_bounds__(256) void k_gemm2(
    const u16* __restrict__ hbuf, const u16* __restrict__ W2t,
    const float* __restrict__ wlist, const int* __restrict__ off, const int* __restrict__ counts,
    u16* __restrict__ ybuf) {
  int e = blockIdx.x >> 5, tm = blockIdx.x & 31;
  int cnt = counts[e];
  if (tm * BM >= cnt) return;
  int seg = off[e];
  int tn = blockIdx.y;   // 0..7
  __shared__ __attribute__((aligned(16))) u16 sA[BM * BK];
  __shared__ __attribute__((aligned(16))) u16 sB[BN * BK];
  int tid = threadIdx.x, lane = tid & 63, wv = tid >> 6;
  int wm = (wv >> 1) << 6, wn = (wv & 1) << 6;
  int rsub = lane >> 3;
  int ch   = lane & 7;
  int cs   = ch ^ rsub;
  const u16* aptr[4]; const u16* bptr[4];
  u16* dA[4]; u16* dB[4];
#pragma unroll
  for (int j = 0; j < 4; j++) {
    int r = wv * 32 + j * 8 + rsub;
    int s = seg + tm * BM + r; if (s > NS - 1) s = NS - 1;
    aptr[j] = hbuf + (size_t)s * HD + cs * 8;
    bptr[j] = W2t + ((size_t)e * DM + tn * BN + r) * HD + cs * 8;
    dA[j] = sA + (wv * 32 + j * 8) * BK;
    dB[j] = sB + (wv * 32 + j * 8) * BK;
  }
  f32x4 acc[4][4];
#pragma unroll
  for (int i = 0; i < 4; i++)
#pragma unroll
    for (int j = 0; j < 4; j++) acc[i][j] = (f32x4){0.f, 0.f, 0.f, 0.f};
  int g = lane >> 4, mr = lane & 15;
#pragma unroll 1
  for (int k0 = 0; k0 < HD; k0 += BK) {
#pragma unroll
    for (int j = 0; j < 4; j++) { glds16(aptr[j] + k0, dA[j]); glds16(bptr[j] + k0, dB[j]); }
    __syncthreads();
    int oa[4], ob[4];
    bf16x8 af[4], bfr[4];
#pragma unroll
    for (int i = 0; i < 4; i++) {
      int ra = wm + i * 16 + mr;
      int rb = wn + i * 16 + mr;
      oa[i] = ra * BK + ((g ^ (ra & 7)) << 3);
      ob[i] = rb * BK + ((g ^ (rb & 7)) << 3);
      af[i]  = *(const bf16x8*)(sA + oa[i]);
      bfr[i] = *(const bf16x8*)(sB + ob[i]);
    }
#pragma unroll
    for (int i = 0; i < 4; i++)
#pragma unroll
      for (int j = 0; j < 4; j++)
        acc[i][j] = __builtin_amdgcn_mfma_f32_16x16x32_bf16(af[i], bfr[j], acc[i][j], 0, 0, 0);
#pragma unroll
    for (int i = 0; i < 4; i++) {
      af[i]  = *(const bf16x8*)(sA + (oa[i] ^ 32));
      bfr[i] = *(const bf16x8*)(sB + (ob[i] ^ 32));
    }
#pragma unroll
    for (int i = 0; i < 4; i++)
#pragma unroll
      for (int j = 0; j < 4; j++)
        acc[i][j] = __builtin_amdgcn_mfma_f32_16x16x32_bf16(af[i], bfr[j], acc[i][j], 0, 0, 0);
    __syncthreads();
  }
  int c = lane & 15;
#pragma unroll
  for (int i = 0; i < 4; i++) {
#pragma unroll
    for (int rr2 = 0; rr2 < 4; rr2++) {
      int row = wm + i * 16 + g * 4 + rr2;
      if (tm * BM + row < cnt) {
        int s = seg + tm * BM + row;
        float wgt = wlist[s];
        size_t rbase = (size_t)s * DM + (size_t)tn * BN + wn + c;
#pragma unroll
        for (int j = 0; j < 4; j++)
          ybuf[rbase + j * 16] = f2b(acc[i][j][rr2] * wgt);
      }
    }
  }
}

// ---------------- combine: out = x + y[slot0] + y[slot1] ----------------
__global__ __launch_bounds__(256) void k_combine(const float* __restrict__ x,
    const u16* __restrict__ ybuf, const int* __restrict__ slots, float* __restrict__ out) {
  int t = blockIdx.x, tid = threadIdx.x;
  int sA = slots[2*t], sB = slots[2*t+1];
  float4 xv = ((const float4*)(x + (size_t)t * DM))[tid];
  ushort4 ya = *(const ushort4*)(ybuf + (size_t)sA * DM + tid * 4);
  ushort4 yb = *(const ushort4*)(ybuf + (size_t)sB * DM + tid * 4);
  float4 o;
  o.x = xv.x + b2f(ya.x) + b2f(yb.x);
  o.y = xv.y + b2f(ya.y) + b2f(yb.y);
  o.z = xv.z + b2f(ya.z) + b2f(yb.z);
  o.w = xv.w + b2f(ya.w) + b2f(yb.w);
  ((float4*)(out + (size_t)t * DM))[tid] = o;
}

extern "C" void kernel_launch(void* const* d_in, const int* in_sizes, int n_in,
                              void* d_out, int out_size, void* d_ws, size_t ws_size,
                              hipStream_t stream) {
  const float* x     = (const float*)d_in[0];
  const float* gamma = (const float*)d_in[1];
  const float* beta  = (const float*)d_in[2];
  const float* rw    = (const float*)d_in[3];
  const float* W1    = (const float*)d_in[4];
  const float* W2    = (const float*)d_in[5];
  float* out = (float*)d_out;

  char* w = (char*)d_ws;
  size_t o = 0;
  auto alloc = [&](size_t bytes) -> void* {
    void* p = w + o; o = (o + bytes + 255) & ~(size_t)255; return p;
  };
  u16*   xnb   = (u16*)  alloc((size_t)NTOK * DM * 2);
  u16*   W1t   = (u16*)  alloc((size_t)NE * HD * DM * 2);
  u16*   W2t   = (u16*)  alloc((size_t)NE * DM * HD * 2);
  u16*   hbuf  = (u16*)  alloc((size_t)NS * HD * 2);
  u16*   ybuf  = (u16*)  alloc((size_t)NS * DM * 2);
  int*   e01   = (int*)  alloc((size_t)NTOK * 2 * 4);
  float* w01   = (float*)alloc((size_t)NTOK * 2 * 4);
  int*   slots = (int*)  alloc((size_t)NTOK * 2 * 4);
  int*   list  = (int*)  alloc((size_t)NS * 4);
  float* wlist = (float*)alloc((size_t)NS * 4);
  int*   meta  = (int*)  alloc(256);          // counts[8], fill[8], off[9]
  int* counts = meta;
  int* fill   = meta + 8;
  int* off    = meta + 16;

  hipMemsetAsync(meta, 0, 256, stream);
  k_ln_router<<<NTOK, 256, 0, stream>>>(x, gamma, beta, rw, xnb, e01, w01, counts);
  k_scan<<<1, 64, 0, stream>>>(counts, off);
  k_bucket<<<NTOK / 256, 256, 0, stream>>>(e01, w01, off, fill, list, wlist, slots);
  k_transpose<<<dim3(DM/64, HD/64, NE), dim3(256), 0, stream>>>(W1, W1t, DM, HD);
  k_transpose<<<dim3(HD/64, DM/64, NE), dim3(256), 0, stream>>>(W2, W2t, HD, DM);
  k_gemm1<<<dim3(NE * 32, HD / BN), 256, 0, stream>>>(xnb, W1t, list, off, counts, hbuf);
  k_gemm2<<<dim3(NE * 32, DM / BN), 256, 0, stream>>>(hbuf, W2t, wlist, off, counts, ybuf);
  k_combine<<<NTOK, 256, 0, stream>>>(x, ybuf, slots, out);
}

// Round 3
// 740.924 us; speedup vs baseline: 2.1476x; 1.6548x over previous
//
#include <hip/hip_runtime.h>
#include <hip/hip_bf16.h>
#include <stdint.h>

#define NTOK 4096
#define DM   1024
#define HD   4096
#define NE   8
#define NS   8192      // NTOK * top_k
#define TEMP 1.5f
#define LNEPS 1e-5f
#define BM 128
#define BN 256
#define BK 32          // one 16x16x32 k-step per iteration

typedef __attribute__((ext_vector_type(8))) short bf16x8;
typedef __attribute__((ext_vector_type(4))) float f32x4;
typedef unsigned short u16;

__device__ inline void glds16(const void* g, void* l) {
  __builtin_amdgcn_global_load_lds((const __attribute__((address_space(1))) unsigned int*)g,
                                   (__attribute__((address_space(3))) unsigned int*)l, 16, 0, 0);
}
__device__ inline u16 f2b(float f) {
  __hip_bfloat16 h = __float2bfloat16(f);
  return *reinterpret_cast<u16*>(&h);
}
__device__ inline float b2f(u16 u) { return __uint_as_float(((unsigned int)u) << 16); }

// ---------------- LayerNorm + router + top2 ----------------
__global__ __launch_bounds__(256) void k_ln_router(
    const float* __restrict__ x, const float* __restrict__ gamma, const float* __restrict__ beta,
    const float* __restrict__ rw, u16* __restrict__ xnb,
    int* __restrict__ e01, float* __restrict__ w01, int* __restrict__ counts) {
  int t = blockIdx.x;
  int tid = threadIdx.x, lane = tid & 63, wv = tid >> 6;
  float4 v = ((const float4*)(x + (size_t)t * DM))[tid];
  float s  = v.x + v.y + v.z + v.w;
  float s2 = v.x*v.x + v.y*v.y + v.z*v.z + v.w*v.w;
  for (int o = 32; o > 0; o >>= 1) { s += __shfl_down(s, o); s2 += __shfl_down(s2, o); }
  __shared__ float rs_[4], rs2_[4];
  if (lane == 0) { rs_[wv] = s; rs2_[wv] = s2; }
  __syncthreads();
  float sum  = rs_[0] + rs_[1] + rs_[2] + rs_[3];
  float sum2 = rs2_[0] + rs2_[1] + rs2_[2] + rs2_[3];
  float mu = sum * (1.f / DM);
  float var = sum2 * (1.f / DM) - mu * mu;
  float rstd = rsqrtf(var + LNEPS);
  float4 g4 = ((const float4*)gamma)[tid];
  float4 b4 = ((const float4*)beta)[tid];
  float n0 = (v.x - mu) * rstd * g4.x + b4.x;
  float n1 = (v.y - mu) * rstd * g4.y + b4.y;
  float n2 = (v.z - mu) * rstd * g4.z + b4.z;
  float n3 = (v.w - mu) * rstd * g4.w + b4.w;
  ushort4 pk; pk.x = f2b(n0); pk.y = f2b(n1); pk.z = f2b(n2); pk.w = f2b(n3);
  *(ushort4*)(xnb + (size_t)t * DM + tid * 4) = pk;
  float p[NE];
#pragma unroll
  for (int e = 0; e < NE; e++) {
    float4 r = ((const float4*)(rw + (size_t)e * DM))[tid];
    p[e] = n0 * r.x + n1 * r.y + n2 * r.z + n3 * r.w;
  }
#pragma unroll
  for (int e = 0; e < NE; e++)
    for (int o = 32; o > 0; o >>= 1) p[e] += __shfl_down(p[e], o);
  __shared__ float plds[4][NE];
  if (lane == 0) {
#pragma unroll
    for (int e = 0; e < NE; e++) plds[wv][e] = p[e];
  }
  __syncthreads();
  if (tid == 0) {
    float lg[NE], mx = -1e30f;
#pragma unroll
    for (int e = 0; e < NE; e++) {
      lg[e] = plds[0][e] + plds[1][e] + plds[2][e] + plds[3][e];
      mx = fmaxf(mx, lg[e]);
    }
    float ex[NE], ssum = 0.f;
#pragma unroll
    for (int e = 0; e < NE; e++) { ex[e] = __expf((lg[e] - mx) * (1.f / TEMP)); ssum += ex[e]; }
    float inv = 1.f / ssum;
    float p0 = -1e30f, p1 = -1e30f; int i0 = 0, i1 = 1;
#pragma unroll
    for (int e = 0; e < NE; e++) {
      float pe = ex[e] * inv;
      if (pe > p0) { p1 = p0; i1 = i0; p0 = pe; i0 = e; }
      else if (pe > p1) { p1 = pe; i1 = e; }
    }
    e01[2*t] = i0; e01[2*t+1] = i1; w01[2*t] = p0; w01[2*t+1] = p1;
    atomicAdd(&counts[i0], 1); atomicAdd(&counts[i1], 1);
  }
}

// ---------------- tiny exclusive scan over 8 counts ----------------
__global__ void k_scan(const int* __restrict__ counts, int* __restrict__ off) {
  if (threadIdx.x == 0) {
    int a = 0;
    for (int e = 0; e < NE; e++) { off[e] = a; a += counts[e]; }
    off[NE] = a;
  }
}

// ---------------- bucket tokens into compact expert lists ----------------
__global__ void k_bucket(const int* __restrict__ e01, const float* __restrict__ w01,
                         const int* __restrict__ off, int* fill, int* __restrict__ list,
                         float* __restrict__ wlist, int* __restrict__ slots) {
  int t = blockIdx.x * blockDim.x + threadIdx.x;
  if (t >= NTOK) return;
  for (int j = 0; j < 2; j++) {
    int e = e01[2*t+j];
    int pos = atomicAdd(&fill[e], 1);
    int s = off[e] + pos;
    list[s] = t; wlist[s] = w01[2*t+j]; slots[2*t+j] = s;
  }
}

// ---------------- transpose + fp32->bf16, 64x64 tile, vectorized ----------------
__global__ __launch_bounds__(256) void k_transpose(const float* __restrict__ in,
                                                   u16* __restrict__ out, int R, int C) {
  __shared__ u16 t[64][68];
  size_t base = (size_t)blockIdx.z * (size_t)R * C;
  int r0 = blockIdx.x << 6, c0 = blockIdx.y << 6;
  int tid = threadIdx.x;
  int rr = tid >> 4, c4 = tid & 15;
#pragma unroll
  for (int p = 0; p < 4; p++) {
    int r = p * 16 + rr;
    float4 v = *(const float4*)(in + base + (size_t)(r0 + r) * C + c0 + c4 * 4);
    ushort4 pk; pk.x = f2b(v.x); pk.y = f2b(v.y); pk.z = f2b(v.z); pk.w = f2b(v.w);
    *(ushort4*)&t[r][c4 * 4] = pk;
  }
  __syncthreads();
#pragma unroll
  for (int p = 0; p < 4; p++) {
    int cc = p * 16 + rr;
    ushort4 o;
    o.x = t[c4*4 + 0][cc]; o.y = t[c4*4 + 1][cc];
    o.z = t[c4*4 + 2][cc]; o.w = t[c4*4 + 3][cc];
    *(ushort4*)(out + base + (size_t)(c0 + cc) * R + r0 + c4 * 4) = o;
  }
}

// Swizzled LDS layout: row-major [row][BK], 4 chunks of 16B per row,
// global chunk g stored at slot g ^ ((row>>1)&3)  -> 2-way (free) bank aliasing.

// ---------------- GEMM1: h = silu(xn @ W1t^T), gathered rows ----------------
__global__ __launch_bounds__(512, 4) void k_gemm1(
    const u16* __restrict__ xnb, const u16* __restrict__ W1t,
    const int* __restrict__ list, const int* __restrict__ off, const int* __restrict__ counts,
    u16* __restrict__ hbuf) {
  // XCD-aware decode: same (e,tm) -> same XCD for all tn (A-tile L2 reuse)
  int bx = blockIdx.x;                 // 0..255
  int xcd = bx & 7, jj = bx >> 3;      // jj 0..31
  int e = jj & 7;
  int tm = ((xcd - e) & 7) + ((jj >> 3) << 3);   // 0..31
  int cnt = counts[e];
  if (tm * BM >= cnt) return;
  int seg = off[e];
  int tn = blockIdx.y;                 // 0..15
  __shared__ __attribute__((aligned(16))) u16 sA[2][BM * BK];
  __shared__ __attribute__((aligned(16))) u16 sB[2][BN * BK];
  int tid = threadIdx.x, lane = tid & 63, wv = tid >> 6;  // 8 waves
  int wm = (wv >> 2) << 6;             // 0 / 64
  int wn = (wv & 3) << 6;              // 0..192
  // staging decode: 64 lanes = 16 rows x 4 chunks
  int r16 = lane >> 2, ch = lane & 3;
  int rowA = (wv << 4) + r16;                          // 0..127
  int gA = ch ^ ((rowA >> 1) & 3);
  int tokA = list[seg + min(tm * BM + rowA, cnt - 1)];
  const u16* pA = xnb + (size_t)tokA * DM + gA * 8;
  int rowB0 = (wv << 5) + r16;                         // 0..255
  int rowB1 = rowB0 + 16;
  int gB0 = ch ^ ((rowB0 >> 1) & 3);
  int gB1 = ch ^ ((rowB1 >> 1) & 3);
  const u16* pB0 = W1t + ((size_t)e * HD + (size_t)tn * BN + rowB0) * DM + gB0 * 8;
  const u16* pB1 = W1t + ((size_t)e * HD + (size_t)tn * BN + rowB1) * DM + gB1 * 8;
  u16* dA  = sA[0] + (wv << 4) * BK;
  u16* dB0 = sB[0] + (wv << 5) * BK;
  u16* dB1 = sB[0] + ((wv << 5) + 16) * BK;
  const int bufo = BM * BK;    // sA buffer stride (u16)
  const int bufoB = BN * BK;
  // fragment offsets (u16 units), fixed per buffer
  int g = lane >> 4, mr = lane & 15;
  int offA[4], offB[4];
#pragma unroll
  for (int i = 0; i < 4; i++) {
    int ra = wm + i * 16 + mr;
    offA[i] = ra * BK + ((g ^ ((ra >> 1) & 3)) << 3);
    int rb = wn + i * 16 + mr;
    offB[i] = rb * BK + ((g ^ ((rb >> 1) & 3)) << 3);
  }
  f32x4 acc[4][4];
#pragma unroll
  for (int i = 0; i < 4; i++)
#pragma unroll
    for (int j = 0; j < 4; j++) acc[i][j] = (f32x4){0.f, 0.f, 0.f, 0.f};
  // prefetch iter 0
  glds16(pA, dA); glds16(pB0, dB0); glds16(pB1, dB1);
  const int ITERS = DM / BK;
#pragma unroll 1
  for (int it = 0; it < ITERS; ++it) {
    __syncthreads();
    int cur = it & 1;
    if (it + 1 < ITERS) {
      int k = (it + 1) * BK;
      int nb = cur ^ 1;
      glds16(pA + k,  dA  + nb * bufo);
      glds16(pB0 + k, dB0 + nb * bufoB);
      glds16(pB1 + k, dB1 + nb * bufoB);
    }
    const u16* A = sA[cur];
    const u16* B = sB[cur];
    bf16x8 af[4], bfr[4];
#pragma unroll
    for (int i = 0; i < 4; i++) { af[i] = *(const bf16x8*)(A + offA[i]); bfr[i] = *(const bf16x8*)(B + offB[i]); }
#pragma unroll
    for (int i = 0; i < 4; i++)
#pragma unroll
      for (int j = 0; j < 4; j++)
        acc[i][j] = __builtin_amdgcn_mfma_f32_16x16x32_bf16(af[i], bfr[j], acc[i][j], 0, 0, 0);
  }
  int c = lane & 15;
#pragma unroll
  for (int i = 0; i < 4; i++) {
#pragma unroll
    for (int rr = 0; rr < 4; rr++) {
      int row = wm + i * 16 + g * 4 + rr;
      if (tm * BM + row < cnt) {
        size_t rbase = (size_t)(seg + tm * BM + row) * HD + (size_t)tn * BN + wn + c;
#pragma unroll
        for (int j = 0; j < 4; j++) {
          float vv = acc[i][j][rr];
          hbuf[rbase + j * 16] = f2b(vv / (1.f + __expf(-vv)));
        }
      }
    }
  }
}

// ---------------- GEMM2: y = (h @ W2t^T) * w_row ----------------
__global__ __launch_bounds__(512, 4) void k_gemm2(
    const u16* __restrict__ hbuf, const u16* __restrict__ W2t,
    const float* __restrict__ wlist, const int* __restrict__ off, const int* __restrict__ counts,
    u16* __restrict__ ybuf) {
  int bx = blockIdx.x;
  int xcd = bx & 7, jj = bx >> 3;
  int e = jj & 7;
  int tm = ((xcd - e) & 7) + ((jj >> 3) << 3);
  int cnt = counts[e];
  if (tm * BM >= cnt) return;
  int seg = off[e];
  int tn = blockIdx.y;                 // 0..3
  __shared__ __attribute__((aligned(16))) u16 sA[2][BM * BK];
  __shared__ __attribute__((aligned(16))) u16 sB[2][BN * BK];
  int tid = threadIdx.x, lane = tid & 63, wv = tid >> 6;
  int wm = (wv >> 2) << 6;
  int wn = (wv & 3) << 6;
  int r16 = lane >> 2, ch = lane & 3;
  int rowA = (wv << 4) + r16;
  int gA = ch ^ ((rowA >> 1) & 3);
  int sa = seg + tm * BM + rowA; if (sa > NS - 1) sa = NS - 1;
  const u16* pA = hbuf + (size_t)sa * HD + gA * 8;
  int rowB0 = (wv << 5) + r16;
  int rowB1 = rowB0 + 16;
  int gB0 = ch ^ ((rowB0 >> 1) & 3);
  int gB1 = ch ^ ((rowB1 >> 1) & 3);
  const u16* pB0 = W2t + ((size_t)e * DM + (size_t)tn * BN + rowB0) * HD + gB0 * 8;
  const u16* pB1 = W2t + ((size_t)e * DM + (size_t)tn * BN + rowB1) * HD + gB1 * 8;
  u16* dA  = sA[0] + (wv << 4) * BK;
  u16* dB0 = sB[0] + (wv << 5) * BK;
  u16* dB1 = sB[0] + ((wv << 5) + 16) * BK;
  const int bufo = BM * BK;
  const int bufoB = BN * BK;
  int g = lane >> 4, mr = lane & 15;
  int offA[4], offB[4];
#pragma unroll
  for (int i = 0; i < 4; i++) {
    int ra = wm + i * 16 + mr;
    offA[i] = ra * BK + ((g ^ ((ra >> 1) & 3)) << 3);
    int rb = wn + i * 16 + mr;
    offB[i] = rb * BK + ((g ^ ((rb >> 1) & 3)) << 3);
  }
  f32x4 acc[4][4];
#pragma unroll
  for (int i = 0; i < 4; i++)
#pragma unroll
    for (int j = 0; j < 4; j++) acc[i][j] = (f32x4){0.f, 0.f, 0.f, 0.f};
  glds16(pA, dA); glds16(pB0, dB0); glds16(pB1, dB1);
  const int ITERS = HD / BK;
#pragma unroll 1
  for (int it = 0; it < ITERS; ++it) {
    __syncthreads();
    int cur = it & 1;
    if (it + 1 < ITERS) {
      int k = (it + 1) * BK;
      int nb = cur ^ 1;
      glds16(pA + k,  dA  + nb * bufo);
      glds16(pB0 + k, dB0 + nb * bufoB);
      glds16(pB1 + k, dB1 + nb * bufoB);
    }
    const u16* A = sA[cur];
    const u16* B = sB[cur];
    bf16x8 af[4], bfr[4];
#pragma unroll
    for (int i = 0; i < 4; i++) { af[i] = *(const bf16x8*)(A + offA[i]); bfr[i] = *(const bf16x8*)(B + offB[i]); }
#pragma unroll
    for (int i = 0; i < 4; i++)
#pragma unroll
      for (int j = 0; j < 4; j++)
        acc[i][j] = __builtin_amdgcn_mfma_f32_16x16x32_bf16(af[i], bfr[j], acc[i][j], 0, 0, 0);
  }
  int c = lane & 15;
#pragma unroll
  for (int i = 0; i < 4; i++) {
#pragma unroll
    for (int rr = 0; rr < 4; rr++) {
      int row = wm + i * 16 + g * 4 + rr;
      if (tm * BM + row < cnt) {
        int s = seg + tm * BM + row;
        float wgt = wlist[s];
        size_t rbase = (size_t)s * DM + (size_t)tn * BN + wn + c;
#pragma unroll
        for (int j = 0; j < 4; j++)
          ybuf[rbase + j * 16] = f2b(acc[i][j][rr] * wgt);
      }
    }
  }
}

// ---------------- combine: out = x + y[slot0] + y[slot1] ----------------
__global__ __launch_bounds__(256) void k_combine(const float* __restrict__ x,
    const u16* __restrict__ ybuf, const int* __restrict__ slots, float* __restrict__ out) {
  int t = blockIdx.x, tid = threadIdx.x;
  int sA = slots[2*t], sB = slots[2*t+1];
  float4 xv = ((const float4*)(x + (size_t)t * DM))[tid];
  ushort4 ya = *(const ushort4*)(ybuf + (size_t)sA * DM + tid * 4);
  ushort4 yb = *(const ushort4*)(ybuf + (size_t)sB * DM + tid * 4);
  float4 o;
  o.x = xv.x + b2f(ya.x) + b2f(yb.x);
  o.y = xv.y + b2f(ya.y) + b2f(yb.y);
  o.z = xv.z + b2f(ya.z) + b2f(yb.z);
  o.w = xv.w + b2f(ya.w) + b2f(yb.w);
  ((float4*)(out + (size_t)t * DM))[tid] = o;
}

extern "C" void kernel_launch(void* const* d_in, const int* in_sizes, int n_in,
                              void* d_out, int out_size, void* d_ws, size_t ws_size,
                              hipStream_t stream) {
  const float* x     = (const float*)d_in[0];
  const float* gamma = (const float*)d_in[1];
  const float* beta  = (const float*)d_in[2];
  const float* rw    = (const float*)d_in[3];
  const float* W1    = (const float*)d_in[4];
  const float* W2    = (const float*)d_in[5];
  float* out = (float*)d_out;

  char* w = (char*)d_ws;
  size_t o = 0;
  auto alloc = [&](size_t bytes) -> void* {
    void* p = w + o; o = (o + bytes + 255) & ~(size_t)255; return p;
  };
  u16*   xnb   = (u16*)  alloc((size_t)NTOK * DM * 2);
  u16*   W1t   = (u16*)  alloc((size_t)NE * HD * DM * 2);
  u16*   W2t   = (u16*)  alloc((size_t)NE * DM * HD * 2);
  u16*   hbuf  = (u16*)  alloc((size_t)NS * HD * 2);
  u16*   ybuf  = (u16*)  alloc((size_t)NS * DM * 2);
  int*   e01   = (int*)  alloc((size_t)NTOK * 2 * 4);
  float* w01   = (float*)alloc((size_t)NTOK * 2 * 4);
  int*   slots = (int*)  alloc((size_t)NTOK * 2 * 4);
  int*   list  = (int*)  alloc((size_t)NS * 4);
  float* wlist = (float*)alloc((size_t)NS * 4);
  int*   meta  = (int*)  alloc(256);          // counts[8], fill[8], off[9]
  int* counts = meta;
  int* fill   = meta + 8;
  int* off    = meta + 16;

  hipMemsetAsync(meta, 0, 256, stream);
  k_ln_router<<<NTOK, 256, 0, stream>>>(x, gamma, beta, rw, xnb, e01, w01, counts);
  k_scan<<<1, 64, 0, stream>>>(counts, off);
  k_bucket<<<NTOK / 256, 256, 0, stream>>>(e01, w01, off, fill, list, wlist, slots);
  k_transpose<<<dim3(DM/64, HD/64, NE), dim3(256), 0, stream>>>(W1, W1t, DM, HD);
  k_transpose<<<dim3(HD/64, DM/64, NE), dim3(256), 0, stream>>>(W2, W2t, HD, DM);
  k_gemm1<<<dim3(NE * 32, HD / BN), 512, 0, stream>>>(xnb, W1t, list, off, counts, hbuf);
  k_gemm2<<<dim3(NE * 32, DM / BN), 512, 0, stream>>>(hbuf, W2t, wlist, off, counts, ybuf);
  k_combine<<<NTOK, 256, 0, stream>>>(x, ybuf, slots, out);
}